// Round 16
// baseline (242.800 us; speedup 1.0000x reference)
//
#include <hip/hip_runtime.h>
#include <hip/hip_bf16.h>
#include <hip/hip_fp16.h>

#define NN 100000     // nodes
#define FIN 128
#define EMB 64
#define BW_SHIFT 8                          // bucket = dst >> 8  (256 nodes)
#define NB_BUCKET ((NN + 255) / 256)        // 391
#define CHUNK 4096                          // binsort chunk

using half8 = __attribute__((ext_vector_type(8))) _Float16;
using f32x4 = __attribute__((ext_vector_type(4))) float;

#define BIN_LDS (CHUNK * 8 + 4 * NB_BUCKET * 4)    // 39024 B
#define GEMM_LDS (FIN * 64 * 2)                    // 16384 B
#define FUSED_LDS (BIN_LDS > GEMM_LDS ? BIN_LDS : GEMM_LDS)

// ----------------------------------------------------- bucket histogram -----
__global__ void bucket_cnt_k(const int* __restrict__ dst, int* __restrict__ bbase,
                             int n_edges) {
    __shared__ int bcnt[NB_BUCKET];
    for (int i = threadIdx.x; i < NB_BUCKET; i += 256) bcnt[i] = 0;
    __syncthreads();
    for (int e = blockIdx.x * 256 + threadIdx.x; e < n_edges; e += gridDim.x * 256)
        atomicAdd(&bcnt[dst[e] >> BW_SHIFT], 1);
    __syncthreads();
    for (int i = threadIdx.x; i < NB_BUCKET; i += 256) {
        int v = bcnt[i];
        if (v) atomicAdd(&bbase[i], v);
    }
}

// ----------------------------------------------------- bucket scan ----------
__global__ void bscan_k(int* __restrict__ bbase, int* __restrict__ bcur, int n_edges) {
    __shared__ int tmp[512];
    int tid = threadIdx.x;
    int v = (tid < NB_BUCKET) ? bbase[tid] : 0;
    tmp[tid] = v; __syncthreads();
    for (int off = 1; off < 512; off <<= 1) {
        int t = (tid >= off) ? tmp[tid - off] : 0; __syncthreads();
        tmp[tid] += t; __syncthreads();
    }
    int excl = tmp[tid] - v;
    if (tid < NB_BUCKET) { bbase[tid] = excl; bcur[tid] = excl; }
    if (tid == NB_BUCKET - 1) bbase[NB_BUCKET] = n_edges;
}

// ---------------------------------------- fused: binsort (A) || GEMM1 -------
__global__ void binsort_gemm_k(const int* __restrict__ src, const int* __restrict__ dst,
                               int* __restrict__ bcur, uint2* __restrict__ pairs,
                               int n_edges, int nBin,
                               const float* __restrict__ X, const float* __restrict__ W,
                               __half* __restrict__ Y, int n_tiles, int nGemm) {
    __shared__ __align__(16) char smraw[FUSED_LDS];
    const int tid = threadIdx.x;

    if (blockIdx.x < nBin) {
        // ---------------- binsort (CHUNK=4096) ----------------
        uint2* sorted = (uint2*)smraw;
        int* lcnt  = (int*)(smraw + CHUNK * 8);
        int* loff  = lcnt + NB_BUCKET;
        int* lpos  = loff + NB_BUCKET;
        int* gbase = lpos + NB_BUCKET;
        const int lane = tid & 63;

        for (int chunk = blockIdx.x; chunk * CHUNK < n_edges; chunk += nBin) {
            for (int i = tid; i < NB_BUCKET; i += 256) lcnt[i] = 0;
            __syncthreads();

            const int ebase = chunk * CHUNK;
            const int nval  = min(CHUNK, n_edges - ebase);
            int d[16], s[16];
#pragma unroll
            for (int j = 0; j < 16; ++j) {
                int k = j * 256 + tid;
                if (k < nval) {
                    int e = ebase + k;
                    d[j] = dst[e]; s[j] = src[e];
                    atomicAdd(&lcnt[d[j] >> BW_SHIFT], 1);
                } else d[j] = -1;
            }
            __syncthreads();

            if (tid < 64) {                 // exclusive scan of lcnt
                int carry = 0;
                for (int seg = 0; seg < (NB_BUCKET + 63) / 64; ++seg) {
                    int i = seg * 64 + lane;
                    int v = (i < NB_BUCKET) ? lcnt[i] : 0;
                    int incl = v;
                    for (int off = 1; off < 64; off <<= 1) {
                        int idx = lane >= off ? lane - off : lane;
                        int t = __shfl(incl, idx, 64);
                        if (lane >= off) incl += t;
                    }
                    if (i < NB_BUCKET) loff[i] = incl - v + carry;
                    carry += __shfl(incl, 63, 64);
                }
            }
            __syncthreads();

            for (int i = tid; i < NB_BUCKET; i += 256) {
                lpos[i] = loff[i];
                int n = lcnt[i];
                gbase[i] = n ? atomicAdd(&bcur[i], n) : 0;
            }
            __syncthreads();

#pragma unroll
            for (int j = 0; j < 16; ++j) {
                if (d[j] >= 0) {
                    int b = d[j] >> BW_SHIFT;
                    int slot = atomicAdd(&lpos[b], 1);
                    sorted[slot] = make_uint2((unsigned)d[j], (unsigned)s[j]);
                }
            }
            __syncthreads();

            for (int i = tid; i < nval; i += 256) {
                uint2 p = sorted[i];
                int b = (int)(p.x >> BW_SHIFT);
                pairs[gbase[b] + (i - loff[b])] = p;   // ~10-entry runs
            }
            __syncthreads();
        }
    } else {
        // ---------------- GEMM1 (no dinv) ----------------
        _Float16* Wl = (_Float16*)smraw;
        for (int i = tid; i < FIN * 64; i += 256) Wl[i] = (_Float16)W[i];
        __syncthreads();

        const int lane = tid & 63;
        const int wid  = tid >> 6;
        const int col0 = lane & 15;
        const int kg   = lane >> 4;

        half8 bf[4][FIN / 32];
#pragma unroll
        for (int t = 0; t < 4; ++t)
#pragma unroll
            for (int s = 0; s < FIN / 32; ++s) {
                half8 b;
#pragma unroll
                for (int j = 0; j < 8; ++j)
                    b[j] = Wl[(s * 32 + kg * 8 + j) * 64 + t * 16 + col0];
                bf[t][s] = b;
            }

        const int gb = blockIdx.x - nBin;
        for (int tile = gb * 4 + wid; tile < n_tiles; tile += nGemm * 4) {
            const int arow = tile * 16 + col0;
            half8 af[FIN / 32];
#pragma unroll
            for (int s = 0; s < FIN / 32; ++s) {
                const float* p = X + (size_t)arow * FIN + s * 32 + kg * 8;
                f32x4 v0 = *(const f32x4*)p;
                f32x4 v1 = *(const f32x4*)(p + 4);
                half8 a;
#pragma unroll
                for (int j = 0; j < 4; ++j) { a[j] = (_Float16)v0[j]; a[4 + j] = (_Float16)v1[j]; }
                af[s] = a;
            }
            f32x4 acc[4];
#pragma unroll
            for (int t = 0; t < 4; ++t) acc[t] = (f32x4){0.f, 0.f, 0.f, 0.f};
#pragma unroll
            for (int s = 0; s < FIN / 32; ++s)
#pragma unroll
                for (int t = 0; t < 4; ++t)
                    acc[t] = __builtin_amdgcn_mfma_f32_16x16x32_f16(af[s], bf[t][s], acc[t], 0, 0, 0);
#pragma unroll
            for (int t = 0; t < 4; ++t)
#pragma unroll
                for (int r = 0; r < 4; ++r) {
                    int row = tile * 16 + kg * 4 + r;
                    Y[(size_t)row * 64 + t * 16 + col0] = __float2half(acc[t][r]);
                }
        }
    }
}

// -------------------------------------------- pass B: per-bucket CSR build --
__global__ void bucket_build_k(const uint2* __restrict__ pairs, const int* __restrict__ bbase,
                               int* __restrict__ rowptr, float* __restrict__ dinv,
                               int* __restrict__ csr, uint2* __restrict__ bufA4,
                               int n_edges) {
    __shared__ int ndeg[256];
    __shared__ int nexcl[256];
    __shared__ int ncur[256];
    const int b   = blockIdx.x;
    const int tid = threadIdx.x;
    const int lo = bbase[b], hi = bbase[b + 1];
    const int n0 = b << BW_SHIFT;
    const int nn = min(256, NN - n0);

    ndeg[tid] = 0;
    __syncthreads();
    for (int i = lo + tid; i < hi; i += 256)
        atomicAdd(&ndeg[(int)pairs[i].x - n0], 1);
    __syncthreads();

    int v = ndeg[tid];
    nexcl[tid] = v;
    __syncthreads();
    for (int off = 1; off < 256; off <<= 1) {
        int t = (tid >= off) ? nexcl[tid - off] : 0;
        __syncthreads();
        nexcl[tid] += t;
        __syncthreads();
    }
    int excl = nexcl[tid] - v;
    float di = rsqrtf((float)(v + 1));

    if (tid < nn) {
        rowptr[n0 + tid] = lo + excl;
        dinv[n0 + tid] = di;
    }
    if (b == NB_BUCKET - 1 && tid == 0) rowptr[NN] = n_edges;
    ncur[tid] = lo + excl;
    __syncthreads();

    for (int i = lo + tid; i < hi; i += 256) {
        uint2 p = pairs[i];
        int pos = atomicAdd(&ncur[(int)p.x - n0], 1);
        csr[pos] = (int)p.y;
    }

    // scale h~ rows of this bucket by dinv (R13-exact form)
    if (tid < nn) {
        uint2* row = bufA4 + (size_t)(n0 + tid) * 16;
#pragma unroll 4
        for (int k = 0; k < 16; ++k) {
            uint2 w = row[k];
            __half2 a = *(__half2*)&w.x, c = *(__half2*)&w.y;
            float2 fa = __half22float2(a), fc = __half22float2(c);
            __half2 oa = __floats2half2_rn(fa.x * di, fa.y * di);
            __half2 oc = __floats2half2_rn(fc.x * di, fc.y * di);
            uint2 o; o.x = *(uint*)&oa; o.y = *(uint*)&oc;
            row[k] = o;
        }
    }
}

// ----------------------------------- gather1 + GEMM2 fused (layer 1+2a) -----
// Gather layer-1 messages (8x8-lane groups, 8 rows in flight), butterfly so
// EVERY lane holds the full relu row, then dot with W2 (fp16 in LDS):
// lane (g,fl) covers features 8fl..8fl+7 x outputs 8g..8g+7; shfl_xor over fl
// completes the 64-dot. Writes bufB = dinv[node] * (h1 @ W2).
__global__ void gather_gemm_k(const uint4* __restrict__ H16, const float* __restrict__ dinv,
                              const int* __restrict__ rowptr, const int* __restrict__ csr,
                              const float* __restrict__ bias, const float* __restrict__ W2,
                              uint4* __restrict__ out16) {
    __shared__ _Float16 W2l[64 * 64];          // 8 KB, [f][o]
    for (int i = threadIdx.x; i < 64 * 64; i += 256) W2l[i] = (_Float16)W2[i];
    __syncthreads();

    int node = (blockIdx.x * blockDim.x + threadIdx.x) >> 6;
    if (node >= NN) return;
    const int lane = threadIdx.x & 63;
    const int g  = lane >> 3;      // output octet / row-load slot
    const int fl = lane & 7;       // feature octet

    const int p0 = rowptr[node], p1 = rowptr[node + 1];

    float acc[8];
#pragma unroll
    for (int k = 0; k < 8; ++k) acc[k] = 0.f;

    if (g == 0) {                  // self-loop row
        uint4 v = H16[(size_t)node * 8 + fl];
        const __half2* h = (const __half2*)&v;
#pragma unroll
        for (int k = 0; k < 4; ++k) {
            float2 f = __half22float2(h[k]);
            acc[2 * k] += f.x; acc[2 * k + 1] += f.y;
        }
    }

    for (int base = p0; base < p1; base += 64) {
        int pos = base + lane;
        int cidx = (pos < p1) ? csr[pos] : 0;       // one coalesced read / chunk
        int m = p1 - base; if (m > 64) m = 64;
        int jmax = (m + 7) >> 3;                    // wave-uniform trip count
#pragma unroll 4
        for (int j = 0; j < jmax; ++j) {
            int nb = (j << 3) + g;
            int s = __shfl(cidx, nb, 64);           // all 64 lanes execute
            if (nb < m) {
                uint4 v = H16[(size_t)s * 8 + fl];
                const __half2* h = (const __half2*)&v;
#pragma unroll
                for (int k = 0; k < 4; ++k) {
                    float2 f = __half22float2(h[k]);
                    acc[2 * k] += f.x; acc[2 * k + 1] += f.y;
                }
            }
        }
    }

    // butterfly: every lane gets the full aggregate for its feature octet
#pragma unroll
    for (int off = 8; off < 64; off <<= 1)
#pragma unroll
        for (int k = 0; k < 8; ++k)
            acc[k] += __shfl_xor(acc[k], off, 64);

    const float di = dinv[node];
    const float4 b0 = ((const float4*)bias)[2 * fl];
    const float4 b1v = ((const float4*)bias)[2 * fl + 1];
    float r[8];                    // h1 features 8fl..8fl+7 (f32, no rounding)
    r[0] = fmaxf(fmaf(acc[0], di, b0.x), 0.f);
    r[1] = fmaxf(fmaf(acc[1], di, b0.y), 0.f);
    r[2] = fmaxf(fmaf(acc[2], di, b0.z), 0.f);
    r[3] = fmaxf(fmaf(acc[3], di, b0.w), 0.f);
    r[4] = fmaxf(fmaf(acc[4], di, b1v.x), 0.f);
    r[5] = fmaxf(fmaf(acc[5], di, b1v.y), 0.f);
    r[6] = fmaxf(fmaf(acc[6], di, b1v.z), 0.f);
    r[7] = fmaxf(fmaf(acc[7], di, b1v.w), 0.f);

    // GEMM2 slice: partial[k] = sum_j r[j] * W2[8fl+j][8g+k]
    float partial[8];
#pragma unroll
    for (int k = 0; k < 8; ++k) partial[k] = 0.f;
#pragma unroll
    for (int j = 0; j < 8; ++j) {
        half8 w = *(const half8*)&W2l[(8 * fl + j) * 64 + 8 * g];
        float rv = r[j];
#pragma unroll
        for (int k = 0; k < 8; ++k)
            partial[k] = fmaf(rv, (float)w[k], partial[k]);
    }
    // reduce over the 8 feature octets (fl): xor 1,2,4
#pragma unroll
    for (int off = 1; off < 8; off <<= 1)
#pragma unroll
        for (int k = 0; k < 8; ++k)
            partial[k] += __shfl_xor(partial[k], off, 64);

    if (fl == 0) {                 // lane (g,0) writes outputs 8g..8g+7
        __half2 h[4];
#pragma unroll
        for (int k = 0; k < 4; ++k)
            h[k] = __floats2half2_rn(partial[2 * k] * di, partial[2 * k + 1] * di);
        out16[(size_t)node * 8 + g] = *(const uint4*)h;
    }
}

// ------------------------------------------------- gather + head (layer 2b) -
__global__ void gather_head_k(const uint4* __restrict__ H16, const float* __restrict__ dinv,
                              const int* __restrict__ rowptr, const int* __restrict__ csr,
                              const float* __restrict__ bias, const float* __restrict__ W3,
                              const float* __restrict__ b3, float* __restrict__ out1) {
    int node = (blockIdx.x * blockDim.x + threadIdx.x) >> 6;
    if (node >= NN) return;
    const int lane = threadIdx.x & 63;
    const int g  = lane >> 3;
    const int fl = lane & 7;

    const int p0 = rowptr[node], p1 = rowptr[node + 1];

    float acc[8];
#pragma unroll
    for (int k = 0; k < 8; ++k) acc[k] = 0.f;

    if (g == 0) {
        uint4 v = H16[(size_t)node * 8 + fl];
        const __half2* h = (const __half2*)&v;
#pragma unroll
        for (int k = 0; k < 4; ++k) {
            float2 f = __half22float2(h[k]);
            acc[2 * k] += f.x; acc[2 * k + 1] += f.y;
        }
    }

    for (int base = p0; base < p1; base += 64) {
        int pos = base + lane;
        int cidx = (pos < p1) ? csr[pos] : 0;
        int m = p1 - base; if (m > 64) m = 64;
        int jmax = (m + 7) >> 3;
#pragma unroll 4
        for (int j = 0; j < jmax; ++j) {
            int nb = (j << 3) + g;
            int s = __shfl(cidx, nb, 64);
            if (nb < m) {
                uint4 v = H16[(size_t)s * 8 + fl];
                const __half2* h = (const __half2*)&v;
#pragma unroll
                for (int k = 0; k < 4; ++k) {
                    float2 f = __half22float2(h[k]);
                    acc[2 * k] += f.x; acc[2 * k + 1] += f.y;
                }
            }
        }
    }

#pragma unroll
    for (int off = 8; off < 64; off <<= 1)
#pragma unroll
        for (int k = 0; k < 8; ++k)
            acc[k] += __shfl_xor(acc[k], off, 64);

    float di = dinv[node];
    float4 b0 = ((const float4*)bias)[2 * fl];
    float4 b1v = ((const float4*)bias)[2 * fl + 1];
    float4 w0 = ((const float4*)W3)[2 * fl];
    float4 w1 = ((const float4*)W3)[2 * fl + 1];
    float partial =
        fmaxf(fmaf(acc[0], di, b0.x), 0.f) * w0.x +
        fmaxf(fmaf(acc[1], di, b0.y), 0.f) * w0.y +
        fmaxf(fmaf(acc[2], di, b0.z), 0.f) * w0.z +
        fmaxf(fmaf(acc[3], di, b0.w), 0.f) * w0.w +
        fmaxf(fmaf(acc[4], di, b1v.x), 0.f) * w1.x +
        fmaxf(fmaf(acc[5], di, b1v.y), 0.f) * w1.y +
        fmaxf(fmaf(acc[6], di, b1v.z), 0.f) * w1.z +
        fmaxf(fmaf(acc[7], di, b1v.w), 0.f) * w1.w;
#pragma unroll
    for (int off = 1; off < 8; off <<= 1)
        partial += __shfl_xor(partial, off, 64);
    if (lane == 0) out1[node] = partial + b3[0];
}

// ---------------------------------------------------------------------------
extern "C" void kernel_launch(void* const* d_in, const int* in_sizes, int n_in,
                              void* d_out, int out_size, void* d_ws, size_t ws_size,
                              hipStream_t stream) {
    const float* x   = (const float*)d_in[0];
    const int*   ei  = (const int*)d_in[1];
    const float* W1  = (const float*)d_in[2];
    const float* b1  = (const float*)d_in[3];
    const float* W2  = (const float*)d_in[4];
    const float* b2  = (const float*)d_in[5];
    const float* W3  = (const float*)d_in[6];
    const float* b3  = (const float*)d_in[7];
    float* out = (float*)d_out;

    const int E = in_sizes[1] / 2;
    const int* src = ei;
    const int* dst = ei + E;

    // workspace layout (4B units):
    // dinv[N] | rowptr[N+1] | bbase[512] | bcur[512] | csr[E] | bufA | bufB
    float* dinv  = (float*)d_ws;
    int* rowptr  = (int*)(dinv + NN);
    int* bbase   = rowptr + NN + 1;
    int* bcur    = bbase + 512;
    int* csr     = bcur + 512;
    __half* bufA = (__half*)(csr + E);
    __half* bufB = bufA + (size_t)NN * EMB;
    uint2* pairs = (uint2*)bufB;               // overlay, CSR-build phase only

    const int B = 256;
    const int gNw = (NN * 64 + B - 1) / B;     // one wave per node
    const int nTiles = NN / 16;                // 6250 exact
    const int gGemm = (nTiles + 3) / 4;        // 1563
    const int nBin  = (E + CHUNK - 1) / CHUNK; // 391 chunks

    // ---- CSR build (R13-exact structure) ----
    hipMemsetAsync(bbase, 0, 512 * sizeof(int), stream);
    bucket_cnt_k<<<512, B, 0, stream>>>(dst, bbase, E);
    bscan_k<<<1, 512, 0, stream>>>(bbase, bcur, E);
    binsort_gemm_k<<<nBin + gGemm, B, 0, stream>>>(src, dst, bcur, pairs, E, nBin,
                                                   x, W1, bufA, nTiles, gGemm);
    bucket_build_k<<<NB_BUCKET, B, 0, stream>>>(pairs, bbase, rowptr, dinv, csr,
                                                (uint2*)bufA, E);

    // ---- layer 1 gather + layer 2 GEMM (fused) ----
    gather_gemm_k<<<gNw, B, 0, stream>>>((const uint4*)bufA, dinv, rowptr, csr, b1,
                                         W2, (uint4*)bufB);

    // ---- layer 2 gather + head (fused) ----
    gather_head_k<<<gNw, B, 0, stream>>>((const uint4*)bufB, dinv, rowptr, csr, b2,
                                         W3, b3, out);
}

// Round 17
// 206.208 us; speedup vs baseline: 1.1775x; 1.1775x over previous
//
#include <hip/hip_runtime.h>
#include <hip/hip_bf16.h>
#include <hip/hip_fp16.h>

#define NN 100000     // nodes
#define FIN 128
#define EMB 64
#define BW_SHIFT 8                          // bucket = dst >> 8  (256 nodes)
#define NB_BUCKET ((NN + 255) / 256)        // 391
#define CHUNK 4096                          // binsort chunk

using half8 = __attribute__((ext_vector_type(8))) _Float16;
using f32x4 = __attribute__((ext_vector_type(4))) float;

#define BIN_LDS (CHUNK * 8 + 4 * NB_BUCKET * 4)    // 39024 B
#define GEMM_LDS (FIN * 64 * 2)                    // 16384 B
#define FUSED_LDS (BIN_LDS > GEMM_LDS ? BIN_LDS : GEMM_LDS)

// ----------------------------------------------------- bucket histogram -----
__global__ void bucket_cnt_k(const int* __restrict__ dst, int* __restrict__ bbase,
                             int n_edges) {
    __shared__ int bcnt[NB_BUCKET];
    for (int i = threadIdx.x; i < NB_BUCKET; i += 256) bcnt[i] = 0;
    __syncthreads();
    for (int e = blockIdx.x * 256 + threadIdx.x; e < n_edges; e += gridDim.x * 256)
        atomicAdd(&bcnt[dst[e] >> BW_SHIFT], 1);
    __syncthreads();
    for (int i = threadIdx.x; i < NB_BUCKET; i += 256) {
        int v = bcnt[i];
        if (v) atomicAdd(&bbase[i], v);
    }
}

// ----------------------------------------------------- bucket scan ----------
__global__ void bscan_k(int* __restrict__ bbase, int* __restrict__ bcur, int n_edges) {
    __shared__ int tmp[512];
    int tid = threadIdx.x;
    int v = (tid < NB_BUCKET) ? bbase[tid] : 0;
    tmp[tid] = v; __syncthreads();
    for (int off = 1; off < 512; off <<= 1) {
        int t = (tid >= off) ? tmp[tid - off] : 0; __syncthreads();
        tmp[tid] += t; __syncthreads();
    }
    int excl = tmp[tid] - v;
    if (tid < NB_BUCKET) { bbase[tid] = excl; bcur[tid] = excl; }
    if (tid == NB_BUCKET - 1) bbase[NB_BUCKET] = n_edges;
}

// ---------------------------------------- fused: binsort (A) || GEMM1 -------
// R13-exact structure; only the global pairs stream is packed to u32:
// packed = (dst&255)<<17 | src   (src < 2^17, dst-local < 2^8).
__global__ void binsort_gemm_k(const int* __restrict__ src, const int* __restrict__ dst,
                               int* __restrict__ bcur, unsigned* __restrict__ pairs,
                               int n_edges, int nBin,
                               const float* __restrict__ X, const float* __restrict__ W,
                               __half* __restrict__ Y, int n_tiles, int nGemm) {
    __shared__ __align__(16) char smraw[FUSED_LDS];
    const int tid = threadIdx.x;

    if (blockIdx.x < nBin) {
        // ---------------- binsort (CHUNK=4096) ----------------
        uint2* sorted = (uint2*)smraw;
        int* lcnt  = (int*)(smraw + CHUNK * 8);
        int* loff  = lcnt + NB_BUCKET;
        int* lpos  = loff + NB_BUCKET;
        int* gbase = lpos + NB_BUCKET;
        const int lane = tid & 63;

        for (int chunk = blockIdx.x; chunk * CHUNK < n_edges; chunk += nBin) {
            for (int i = tid; i < NB_BUCKET; i += 256) lcnt[i] = 0;
            __syncthreads();

            const int ebase = chunk * CHUNK;
            const int nval  = min(CHUNK, n_edges - ebase);
            int d[16], s[16];
#pragma unroll
            for (int j = 0; j < 16; ++j) {
                int k = j * 256 + tid;
                if (k < nval) {
                    int e = ebase + k;
                    d[j] = dst[e]; s[j] = src[e];
                    atomicAdd(&lcnt[d[j] >> BW_SHIFT], 1);
                } else d[j] = -1;
            }
            __syncthreads();

            if (tid < 64) {                 // exclusive scan of lcnt
                int carry = 0;
                for (int seg = 0; seg < (NB_BUCKET + 63) / 64; ++seg) {
                    int i = seg * 64 + lane;
                    int v = (i < NB_BUCKET) ? lcnt[i] : 0;
                    int incl = v;
                    for (int off = 1; off < 64; off <<= 1) {
                        int idx = lane >= off ? lane - off : lane;
                        int t = __shfl(incl, idx, 64);
                        if (lane >= off) incl += t;
                    }
                    if (i < NB_BUCKET) loff[i] = incl - v + carry;
                    carry += __shfl(incl, 63, 64);
                }
            }
            __syncthreads();

            for (int i = tid; i < NB_BUCKET; i += 256) {
                lpos[i] = loff[i];
                int n = lcnt[i];
                gbase[i] = n ? atomicAdd(&bcur[i], n) : 0;
            }
            __syncthreads();

#pragma unroll
            for (int j = 0; j < 16; ++j) {
                if (d[j] >= 0) {
                    int b = d[j] >> BW_SHIFT;
                    int slot = atomicAdd(&lpos[b], 1);
                    sorted[slot] = make_uint2((unsigned)d[j], (unsigned)s[j]);
                }
            }
            __syncthreads();

            for (int i = tid; i < nval; i += 256) {
                uint2 p = sorted[i];
                int b = (int)(p.x >> BW_SHIFT);
                unsigned packed = ((p.x & 255u) << 17) | p.y;
                pairs[gbase[b] + (i - loff[b])] = packed;   // ~10-entry runs, 4B each
            }
            __syncthreads();
        }
    } else {
        // ---------------- GEMM1 (no dinv) ----------------
        _Float16* Wl = (_Float16*)smraw;
        for (int i = tid; i < FIN * 64; i += 256) Wl[i] = (_Float16)W[i];
        __syncthreads();

        const int lane = tid & 63;
        const int wid  = tid >> 6;
        const int col0 = lane & 15;
        const int kg   = lane >> 4;

        half8 bf[4][FIN / 32];
#pragma unroll
        for (int t = 0; t < 4; ++t)
#pragma unroll
            for (int s = 0; s < FIN / 32; ++s) {
                half8 b;
#pragma unroll
                for (int j = 0; j < 8; ++j)
                    b[j] = Wl[(s * 32 + kg * 8 + j) * 64 + t * 16 + col0];
                bf[t][s] = b;
            }

        const int gb = blockIdx.x - nBin;
        for (int tile = gb * 4 + wid; tile < n_tiles; tile += nGemm * 4) {
            const int arow = tile * 16 + col0;
            half8 af[FIN / 32];
#pragma unroll
            for (int s = 0; s < FIN / 32; ++s) {
                const float* p = X + (size_t)arow * FIN + s * 32 + kg * 8;
                f32x4 v0 = *(const f32x4*)p;
                f32x4 v1 = *(const f32x4*)(p + 4);
                half8 a;
#pragma unroll
                for (int j = 0; j < 4; ++j) { a[j] = (_Float16)v0[j]; a[4 + j] = (_Float16)v1[j]; }
                af[s] = a;
            }
            f32x4 acc[4];
#pragma unroll
            for (int t = 0; t < 4; ++t) acc[t] = (f32x4){0.f, 0.f, 0.f, 0.f};
#pragma unroll
            for (int s = 0; s < FIN / 32; ++s)
#pragma unroll
                for (int t = 0; t < 4; ++t)
                    acc[t] = __builtin_amdgcn_mfma_f32_16x16x32_f16(af[s], bf[t][s], acc[t], 0, 0, 0);
#pragma unroll
            for (int t = 0; t < 4; ++t)
#pragma unroll
                for (int r = 0; r < 4; ++r) {
                    int row = tile * 16 + kg * 4 + r;
                    Y[(size_t)row * 64 + t * 16 + col0] = __float2half(acc[t][r]);
                }
        }
    }
}

// -------------------------------------------- pass B: per-bucket CSR build --
__global__ void bucket_build_k(const unsigned* __restrict__ pairs, const int* __restrict__ bbase,
                               int* __restrict__ rowptr, float* __restrict__ dinv,
                               int* __restrict__ csr, uint2* __restrict__ bufA4,
                               int n_edges) {
    __shared__ int ndeg[256];
    __shared__ int nexcl[256];
    __shared__ int ncur[256];
    const int b   = blockIdx.x;
    const int tid = threadIdx.x;
    const int lo = bbase[b], hi = bbase[b + 1];
    const int n0 = b << BW_SHIFT;
    const int nn = min(256, NN - n0);

    ndeg[tid] = 0;
    __syncthreads();
    for (int i = lo + tid; i < hi; i += 256)
        atomicAdd(&ndeg[pairs[i] >> 17], 1);
    __syncthreads();

    int v = ndeg[tid];
    nexcl[tid] = v;
    __syncthreads();
    for (int off = 1; off < 256; off <<= 1) {
        int t = (tid >= off) ? nexcl[tid - off] : 0;
        __syncthreads();
        nexcl[tid] += t;
        __syncthreads();
    }
    int excl = nexcl[tid] - v;
    float di = rsqrtf((float)(v + 1));

    if (tid < nn) {
        rowptr[n0 + tid] = lo + excl;
        dinv[n0 + tid] = di;
    }
    if (b == NB_BUCKET - 1 && tid == 0) rowptr[NN] = n_edges;
    ncur[tid] = lo + excl;
    __syncthreads();

    for (int i = lo + tid; i < hi; i += 256) {
        unsigned p = pairs[i];
        int pos = atomicAdd(&ncur[p >> 17], 1);
        csr[pos] = (int)(p & 0x1FFFFu);
    }

    // scale h~ rows of this bucket by dinv (R13-exact form)
    if (tid < nn) {
        uint2* row = bufA4 + (size_t)(n0 + tid) * 16;
#pragma unroll 4
        for (int k = 0; k < 16; ++k) {
            uint2 w = row[k];
            __half2 a = *(__half2*)&w.x, c = *(__half2*)&w.y;
            float2 fa = __half22float2(a), fc = __half22float2(c);
            __half2 oa = __floats2half2_rn(fa.x * di, fa.y * di);
            __half2 oc = __floats2half2_rn(fc.x * di, fc.y * di);
            uint2 o; o.x = *(uint*)&oa; o.y = *(uint*)&oc;
            row[k] = o;
        }
    }
}

// ------------------------------------------------------------ MFMA GEMM ----
template <int K, typename TIN>
__global__ void gemm_mfma_k(const TIN* __restrict__ X, const float* __restrict__ W,
                            const float* __restrict__ dinv, __half* __restrict__ Y,
                            int n_tiles) {
    __shared__ _Float16 Wl[K * 64];
    for (int i = threadIdx.x; i < K * 64; i += 256) Wl[i] = (_Float16)W[i];
    __syncthreads();

    const int lane = threadIdx.x & 63;
    const int wid  = threadIdx.x >> 6;
    const int col0 = lane & 15;
    const int kg   = lane >> 4;

    half8 bf[4][K / 32];
#pragma unroll
    for (int t = 0; t < 4; ++t)
#pragma unroll
        for (int s = 0; s < K / 32; ++s) {
            half8 b;
#pragma unroll
            for (int j = 0; j < 8; ++j)
                b[j] = Wl[(s * 32 + kg * 8 + j) * 64 + t * 16 + col0];
            bf[t][s] = b;
        }

    const int nwaves = gridDim.x * 4;
    for (int tile = blockIdx.x * 4 + wid; tile < n_tiles; tile += nwaves) {
        const int row0 = tile * 16;
        const int arow = row0 + col0;
        half8 af[K / 32];
#pragma unroll
        for (int s = 0; s < K / 32; ++s) {
            if constexpr (sizeof(TIN) == 4) {
                const float* p = (const float*)X + (size_t)arow * K + s * 32 + kg * 8;
                f32x4 v0 = *(const f32x4*)p;
                f32x4 v1 = *(const f32x4*)(p + 4);
                half8 a;
#pragma unroll
                for (int j = 0; j < 4; ++j) { a[j] = (_Float16)v0[j]; a[4 + j] = (_Float16)v1[j]; }
                af[s] = a;
            } else {
                const __half* p = (const __half*)X + (size_t)arow * K + s * 32 + kg * 8;
                af[s] = *(const half8*)p;
            }
        }
        f32x4 acc[4];
#pragma unroll
        for (int t = 0; t < 4; ++t) acc[t] = (f32x4){0.f, 0.f, 0.f, 0.f};
#pragma unroll
        for (int s = 0; s < K / 32; ++s)
#pragma unroll
            for (int t = 0; t < 4; ++t)
                acc[t] = __builtin_amdgcn_mfma_f32_16x16x32_f16(af[s], bf[t][s], acc[t], 0, 0, 0);

        float dv[4];
#pragma unroll
        for (int r = 0; r < 4; ++r) dv[r] = dinv[row0 + kg * 4 + r];
#pragma unroll
        for (int t = 0; t < 4; ++t)
#pragma unroll
            for (int r = 0; r < 4; ++r) {
                int row = row0 + kg * 4 + r;
                Y[(size_t)row * 64 + t * 16 + col0] = __float2half(acc[t][r] * dv[r]);
            }
    }
}

// --------------------------------------------------------------- gather -----
template <bool HEAD>
__global__ void gather_k(const uint4* __restrict__ H16, const float* __restrict__ dinv,
                         const int* __restrict__ rowptr, const int* __restrict__ csr,
                         const float* __restrict__ bias, uint4* __restrict__ out16,
                         const float* __restrict__ W3, const float* __restrict__ b3,
                         float* __restrict__ out1) {
    int node = (blockIdx.x * blockDim.x + threadIdx.x) >> 6;
    if (node >= NN) return;
    const int lane = threadIdx.x & 63;
    const int g  = lane >> 3;      // group 0..7 (row slot)
    const int fl = lane & 7;       // feature 8-pack

    const int p0 = rowptr[node], p1 = rowptr[node + 1];

    float acc[8];
#pragma unroll
    for (int k = 0; k < 8; ++k) acc[k] = 0.f;

    if (g == 0) {                  // self-loop row
        uint4 v = H16[(size_t)node * 8 + fl];
        const __half2* h = (const __half2*)&v;
#pragma unroll
        for (int k = 0; k < 4; ++k) {
            float2 f = __half22float2(h[k]);
            acc[2 * k] += f.x; acc[2 * k + 1] += f.y;
        }
    }

    for (int base = p0; base < p1; base += 64) {
        int pos = base + lane;
        int cidx = (pos < p1) ? csr[pos] : 0;       // one coalesced read / chunk
        int m = p1 - base; if (m > 64) m = 64;
        int jmax = (m + 7) >> 3;                    // wave-uniform trip count
#pragma unroll 4
        for (int j = 0; j < jmax; ++j) {
            int nb = (j << 3) + g;                  // this group's neighbor slot
            int s = __shfl(cidx, nb, 64);           // all 64 lanes execute
            if (nb < m) {
                uint4 v = H16[(size_t)s * 8 + fl];
                const __half2* h = (const __half2*)&v;
#pragma unroll
                for (int k = 0; k < 4; ++k) {
                    float2 f = __half22float2(h[k]);
                    acc[2 * k] += f.x; acc[2 * k + 1] += f.y;
                }
            }
        }
    }

#pragma unroll
    for (int off = 8; off < 64; off <<= 1)
#pragma unroll
        for (int k = 0; k < 8; ++k)
            acc[k] += __shfl_xor(acc[k], off, 64);

    float di = dinv[node];
    float4 b0 = ((const float4*)bias)[2 * fl];
    float4 b1v = ((const float4*)bias)[2 * fl + 1];
    float r[8];
    r[0] = fmaxf(fmaf(acc[0], di, b0.x), 0.f);
    r[1] = fmaxf(fmaf(acc[1], di, b0.y), 0.f);
    r[2] = fmaxf(fmaf(acc[2], di, b0.z), 0.f);
    r[3] = fmaxf(fmaf(acc[3], di, b0.w), 0.f);
    r[4] = fmaxf(fmaf(acc[4], di, b1v.x), 0.f);
    r[5] = fmaxf(fmaf(acc[5], di, b1v.y), 0.f);
    r[6] = fmaxf(fmaf(acc[6], di, b1v.z), 0.f);
    r[7] = fmaxf(fmaf(acc[7], di, b1v.w), 0.f);

    if constexpr (HEAD) {
        float4 w0 = ((const float4*)W3)[2 * fl];
        float4 w1 = ((const float4*)W3)[2 * fl + 1];
        float partial = r[0] * w0.x + r[1] * w0.y + r[2] * w0.z + r[3] * w0.w
                      + r[4] * w1.x + r[5] * w1.y + r[6] * w1.z + r[7] * w1.w;
#pragma unroll
        for (int off = 1; off < 8; off <<= 1)
            partial += __shfl_xor(partial, off, 64);
        if (lane == 0) out1[node] = partial + b3[0];
    } else {
        if (g == 0) {
            __half2 h[4];
#pragma unroll
            for (int k = 0; k < 4; ++k) h[k] = __floats2half2_rn(r[2 * k], r[2 * k + 1]);
            out16[(size_t)node * 8 + fl] = *(const uint4*)h;
        }
    }
}

// ---------------------------------------------------------------------------
extern "C" void kernel_launch(void* const* d_in, const int* in_sizes, int n_in,
                              void* d_out, int out_size, void* d_ws, size_t ws_size,
                              hipStream_t stream) {
    const float* x   = (const float*)d_in[0];
    const int*   ei  = (const int*)d_in[1];
    const float* W1  = (const float*)d_in[2];
    const float* b1  = (const float*)d_in[3];
    const float* W2  = (const float*)d_in[4];
    const float* b2  = (const float*)d_in[5];
    const float* W3  = (const float*)d_in[6];
    const float* b3  = (const float*)d_in[7];
    float* out = (float*)d_out;

    const int E = in_sizes[1] / 2;
    const int* src = ei;
    const int* dst = ei + E;

    // workspace layout (4B units):
    // dinv[N] | rowptr[N+1] | bbase[512] | bcur[512] | csr[E] | bufA | bufB
    // pairs[E] (u32) overlays bufB during CSR build only.
    float* dinv  = (float*)d_ws;
    int* rowptr  = (int*)(dinv + NN);
    int* bbase   = rowptr + NN + 1;
    int* bcur    = bbase + 512;
    int* csr     = bcur + 512;
    __half* bufA = (__half*)(csr + E);
    __half* bufB = bufA + (size_t)NN * EMB;
    unsigned* pairs = (unsigned*)bufB;         // overlay, CSR-build phase only

    const int B = 256;
    const int gNw = (NN * 64 + B - 1) / B;     // one wave per node
    const int nTiles = NN / 16;                // 6250 exact
    const int gGemm = (nTiles + 3) / 4;        // 1563
    const int nBin  = (E + CHUNK - 1) / CHUNK; // 391 chunks

    // ---- CSR build ----
    hipMemsetAsync(bbase, 0, 512 * sizeof(int), stream);
    bucket_cnt_k<<<512, B, 0, stream>>>(dst, bbase, E);
    bscan_k<<<1, 512, 0, stream>>>(bbase, bcur, E);
    binsort_gemm_k<<<nBin + gGemm, B, 0, stream>>>(src, dst, bcur, pairs, E, nBin,
                                                   x, W1, bufA, nTiles, gGemm);
    bucket_build_k<<<NB_BUCKET, B, 0, stream>>>(pairs, bbase, rowptr, dinv, csr,
                                                (uint2*)bufA, E);

    // ---- layer 1 aggregation ----
    gather_k<false><<<gNw, B, 0, stream>>>((const uint4*)bufA, dinv, rowptr, csr, b1,
                                           (uint4*)bufB, nullptr, nullptr, nullptr);

    // ---- layer 2 + fused head ----
    gemm_mfma_k<EMB, __half><<<gGemm, B, 0, stream>>>(bufB, W2, dinv, bufA, nTiles);
    gather_k<true><<<gNw, B, 0, stream>>>((const uint4*)bufA, dinv, rowptr, csr, b2,
                                          nullptr, W3, b3, out);
}